// Round 1
// baseline (900.519 us; speedup 1.0000x reference)
//
#include <hip/hip_runtime.h>
#include <stdint.h>

// Problem constants (match reference): N=262144 rows, C=256 channels, K=256 codes.
#define CCH   256
#define KK    256
#define ROWS_PER_BLOCK 512   // rows per gather block chunk
#define NGROUPS 16           // 16-channel groups -> 16 KB LDS -> 8 blocks/CU
#define GCH   (CCH / NGROUPS)

typedef int   i32x4 __attribute__((ext_vector_type(4)));
typedef float f32x4 __attribute__((ext_vector_type(4)));

// ---------------------------------------------------------------------------
// Pass 1: compress white_table int32 -> uint8 (values are codes in [0,256)).
// ---------------------------------------------------------------------------
__global__ __launch_bounds__(256) void compress_table_kernel(
    const int4* __restrict__ t, uchar4* __restrict__ o, int n4) {
  int i = blockIdx.x * 256 + threadIdx.x;
  if (i < n4) {
    int4 v = t[i];
    o[i] = make_uchar4((unsigned char)v.x, (unsigned char)v.y,
                       (unsigned char)v.z, (unsigned char)v.w);
  }
}

// ---------------------------------------------------------------------------
// Pass 2: fused double-gather, latency-optimized.
//   g = blockIdx.x % 16 -> 16-channel group. XCD swizzle: consecutive blockIdx
//   round-robin the 8 XCDs, so groups g and g+8 share an XCD -> 2 MB of u8
//   table resident per 4 MB L2.
//   16 KB LDS codebook slice -> 8 blocks/CU (wave-capped), vs 5 before.
//   Two rows per inner iteration: 4 streaming loads + 8 independent table
//   gathers in flight per thread. Streaming traffic is non-temporal so it
//   does not evict the table slice from L2.
// ---------------------------------------------------------------------------
template <typename TabT>
__global__ __launch_bounds__(256, 8) void gather_kernel(
    const i32x4* __restrict__ left, const i32x4* __restrict__ right,
    const TabT* __restrict__ tab, const float* __restrict__ cb,
    f32x4* __restrict__ out, int nrows) {
  __shared__ float cbs[GCH * KK];  // 16 KB

  const int g     = blockIdx.x & (NGROUPS - 1);
  const int chunk = blockIdx.x / NGROUPS;
  const int q     = threadIdx.x & 3;    // channel quad within group (4 quads)
  const int rsub  = threadIdx.x >> 2;   // 0..63

  // Stage this group's codebook slice into LDS (4096 floats = 1024 float4).
  {
    const f32x4* cbg = (const f32x4*)(cb + (size_t)(g * GCH) * KK);
    f32x4* cbl = (f32x4*)cbs;
#pragma unroll
    for (int i = 0; i < 4; ++i) cbl[threadIdx.x + i * 256] = cbg[threadIdx.x + i * 256];
  }
  __syncthreads();

  const int cbase  = g * GCH + q * 4;                // first of 4 channels
  const TabT* t0   = tab + (size_t)cbase * (KK * KK);
  const int vecoff = g * 4 + q;                      // int4 slot within a row (row = 64 int4)
  const float* cq  = cbs + (q * 4) * KK;             // this quad's codebook rows

  const int rbase = chunk * ROWS_PER_BLOCK;
#pragma unroll
  for (int it = 0; it < ROWS_PER_BLOCK / 128; ++it) {
    const int r0 = rbase + it * 128 + rsub;
    if (r0 >= nrows) break;
    const int r1 = r0 + 64;
    const unsigned v0 = (unsigned)r0 * 64u + (unsigned)vecoff;
    const unsigned v1 = (unsigned)r1 * 64u + (unsigned)vecoff;

    if (r1 < nrows) {
      // --- issue all 4 streaming loads ---
      i32x4 L0 = __builtin_nontemporal_load(&left[v0]);
      i32x4 R0 = __builtin_nontemporal_load(&right[v0]);
      i32x4 L1 = __builtin_nontemporal_load(&left[v1]);
      i32x4 R1 = __builtin_nontemporal_load(&right[v1]);

      // --- 8 independent table gathers ---
      unsigned c00 = (unsigned)t0[          (unsigned)(L0[0] * KK + R0[0])];
      unsigned c01 = (unsigned)t0[ 65536u + (unsigned)(L0[1] * KK + R0[1])];
      unsigned c02 = (unsigned)t0[131072u + (unsigned)(L0[2] * KK + R0[2])];
      unsigned c03 = (unsigned)t0[196608u + (unsigned)(L0[3] * KK + R0[3])];
      unsigned c10 = (unsigned)t0[          (unsigned)(L1[0] * KK + R1[0])];
      unsigned c11 = (unsigned)t0[ 65536u + (unsigned)(L1[1] * KK + R1[1])];
      unsigned c12 = (unsigned)t0[131072u + (unsigned)(L1[2] * KK + R1[2])];
      unsigned c13 = (unsigned)t0[196608u + (unsigned)(L1[3] * KK + R1[3])];

      f32x4 o0, o1;
      o0[0] = cq[         c00];
      o0[1] = cq[  KK   + c01];
      o0[2] = cq[2*KK   + c02];
      o0[3] = cq[3*KK   + c03];
      o1[0] = cq[         c10];
      o1[1] = cq[  KK   + c11];
      o1[2] = cq[2*KK   + c12];
      o1[3] = cq[3*KK   + c13];
      __builtin_nontemporal_store(o0, &out[v0]);
      __builtin_nontemporal_store(o1, &out[v1]);
    } else {
      // tail: single row
      i32x4 L0 = __builtin_nontemporal_load(&left[v0]);
      i32x4 R0 = __builtin_nontemporal_load(&right[v0]);
      unsigned c00 = (unsigned)t0[          (unsigned)(L0[0] * KK + R0[0])];
      unsigned c01 = (unsigned)t0[ 65536u + (unsigned)(L0[1] * KK + R0[1])];
      unsigned c02 = (unsigned)t0[131072u + (unsigned)(L0[2] * KK + R0[2])];
      unsigned c03 = (unsigned)t0[196608u + (unsigned)(L0[3] * KK + R0[3])];
      f32x4 o0;
      o0[0] = cq[         c00];
      o0[1] = cq[  KK   + c01];
      o0[2] = cq[2*KK   + c02];
      o0[3] = cq[3*KK   + c03];
      __builtin_nontemporal_store(o0, &out[v0]);
    }
  }
}

extern "C" void kernel_launch(void* const* d_in, const int* in_sizes, int n_in,
                              void* d_out, int out_size, void* d_ws, size_t ws_size,
                              hipStream_t stream) {
  const int*   left  = (const int*)d_in[0];
  const int*   right = (const int*)d_in[1];
  const int*   wt    = (const int*)d_in[2];   // [C, K, K] int32
  const float* cb    = (const float*)d_in[3]; // [C, K] float32
  float* out = (float*)d_out;

  const int nrows = in_sizes[0] / CCH;        // 262144
  const int tab_elems = CCH * KK * KK;        // 16,777,216
  const int chunks = (nrows + ROWS_PER_BLOCK - 1) / ROWS_PER_BLOCK;
  const int blocks = chunks * NGROUPS;

  if (ws_size >= (size_t)tab_elems) {
    unsigned char* tab8 = (unsigned char*)d_ws;
    int n4 = tab_elems / 4;
    compress_table_kernel<<<n4 / 256, 256, 0, stream>>>(
        (const int4*)wt, (uchar4*)tab8, n4);
    gather_kernel<unsigned char><<<blocks, 256, 0, stream>>>(
        (const i32x4*)left, (const i32x4*)right, tab8, cb, (f32x4*)out, nrows);
  } else {
    // Fallback: gather directly from the int32 table (slower, always correct).
    gather_kernel<int><<<blocks, 256, 0, stream>>>(
        (const i32x4*)left, (const i32x4*)right, wt, cb, (f32x4*)out, nrows);
  }
}

// Round 2
// 740.462 us; speedup vs baseline: 1.2162x; 1.2162x over previous
//
#include <hip/hip_runtime.h>
#include <stdint.h>

// Problem constants: N=262144 rows, C=256 channels, K=256 codes.
#define CCH 256
#define KK  256

typedef int   i32x4 __attribute__((ext_vector_type(4)));
typedef float f32x4 __attribute__((ext_vector_type(4)));
typedef unsigned short u16x8 __attribute__((ext_vector_type(8)));

// ---------------------------------------------------------------------------
// K0: compress white_table int32 -> uint8 (values are codes in [0,256)).
// ---------------------------------------------------------------------------
__global__ __launch_bounds__(256) void compress_table_kernel(
    const int4* __restrict__ t, uchar4* __restrict__ o, int n4) {
  int i = blockIdx.x * 256 + threadIdx.x;
  if (i < n4) {
    int4 v = t[i];
    o[i] = make_uchar4((unsigned char)v.x, (unsigned char)v.y,
                       (unsigned char)v.z, (unsigned char)v.w);
  }
}

// ---------------------------------------------------------------------------
// K1: transpose + pack.  L,R [N,C] i32  ->  LRt [C, nslice] u16 = l*256+r
// (the packed u16 IS the table index).  64n x 64c tiles via LDS; both global
// sides fully coalesced.
// ---------------------------------------------------------------------------
__global__ __launch_bounds__(256) void transpose_pack_kernel(
    const int* __restrict__ L, const int* __restrict__ R,
    unsigned short* __restrict__ LRt, int n0_base, int nslice) {
  __shared__ unsigned short tile[64][66];  // +2 pad: conflict-free both phases
  const int ntn  = nslice >> 6;
  const int tn   = blockIdx.x % ntn;
  const int tc   = blockIdx.x / ntn;       // 0..3
  const int lane = threadIdx.x & 63;       // c within tile (read) / n (write)
  const int ty   = threadIdx.x >> 6;       // 0..3
  const int gn0  = n0_base + tn * 64;
  const int c0   = tc * 64;
#pragma unroll
  for (int p = 0; p < 16; ++p) {
    const int n = p * 4 + ty;
    const size_t gi = (size_t)(gn0 + n) * CCH + c0 + lane;
    tile[lane][n] = (unsigned short)((L[gi] << 8) | R[gi]);
  }
  __syncthreads();
#pragma unroll
  for (int p = 0; p < 16; ++p) {
    const int ch = p * 4 + ty;
    LRt[(size_t)(c0 + ch) * nslice + tn * 64 + lane] = tile[ch][lane];
  }
}

// ---------------------------------------------------------------------------
// K2: per-channel code gather with the 64 KB table in LDS.
// blockIdx = sub*256 + c  (c varies fastest -> per-XCD L2 partitions tables).
// Reads LRt[c] contiguously (u16x8 = 16B/lane), ds_read_u8 gathers, writes
// packed u8 codes (8B/lane).
// ---------------------------------------------------------------------------
__global__ __launch_bounds__(256) void code_gather_kernel(
    const unsigned short* __restrict__ LRt, const unsigned char* __restrict__ tab8,
    unsigned char* __restrict__ codes, int nslice, int nsub) {
  __shared__ unsigned char tabs[KK * KK];  // 64 KB
  const int c   = blockIdx.x & (CCH - 1);
  const int sub = blockIdx.x >> 8;
  const int chunk = nslice / nsub;         // multiple of 8192
  {
    const int4* src = (const int4*)(tab8 + (size_t)c * (KK * KK));
    int4* dst = (int4*)tabs;
#pragma unroll
    for (int i = 0; i < 16; ++i) dst[threadIdx.x + 256 * i] = src[threadIdx.x + 256 * i];
  }
  __syncthreads();
  const size_t base = (size_t)c * nslice + (size_t)sub * chunk;
  const u16x8* __restrict__ in   = (const u16x8*)(LRt + base);
  uint2*       __restrict__ outp = (uint2*)(codes + base);
  const int iters = chunk >> 13;           // / 8192 elems per block-iter
  for (int it = 0; it < iters; ++it) {
    u16x8 v0 = in[(it * 4 + 0) * 256 + threadIdx.x];
    u16x8 v1 = in[(it * 4 + 1) * 256 + threadIdx.x];
    u16x8 v2 = in[(it * 4 + 2) * 256 + threadIdx.x];
    u16x8 v3 = in[(it * 4 + 3) * 256 + threadIdx.x];
#define PACK8(v, slot)                                                         \
    {                                                                          \
      unsigned lo = (unsigned)tabs[v[0]] | ((unsigned)tabs[v[1]] << 8) |       \
                    ((unsigned)tabs[v[2]] << 16) | ((unsigned)tabs[v[3]] << 24);\
      unsigned hi = (unsigned)tabs[v[4]] | ((unsigned)tabs[v[5]] << 8) |       \
                    ((unsigned)tabs[v[6]] << 16) | ((unsigned)tabs[v[7]] << 24);\
      outp[(it * 4 + slot) * 256 + threadIdx.x] = make_uint2(lo, hi);          \
    }
    PACK8(v0, 0) PACK8(v1, 1) PACK8(v2, 2) PACK8(v3, 3)
#undef PACK8
  }
}

// ---------------------------------------------------------------------------
// K3: codebook lookup + transpose back.  codes [C, nslice] u8 -> out [N, C]
// f32.  Tile 256n x 32c; 32 codebooks (32 KB) + code tile in LDS; stores are
// 128 B contiguous per half-wave.
// ---------------------------------------------------------------------------
__global__ __launch_bounds__(256) void codebook_transpose_kernel(
    const unsigned char* __restrict__ codes, const float* __restrict__ cb,
    float* __restrict__ out, int n0_base, int nslice) {
  __shared__ float cbs[32 * KK];           // 32 KB
  __shared__ unsigned int ctile[32 * 65];  // 8.3 KB, pitch 65 dwords = 260 B
  const int ntiles = nslice >> 8;
  const int tn = blockIdx.x % ntiles;
  const int tc = blockIdx.x / ntiles;      // 0..7
  const int c0 = tc * 32;
  {
    const f32x4* cbg = (const f32x4*)(cb + (size_t)c0 * KK);
    f32x4* cbl = (f32x4*)cbs;
#pragma unroll
    for (int i = 0; i < 8; ++i) cbl[threadIdx.x + 256 * i] = cbg[threadIdx.x + 256 * i];
  }
  {
    const int lane = threadIdx.x & 63;     // n-dword within tile
    const int ty   = threadIdx.x >> 6;     // 0..3
    const size_t nbase = (size_t)tn * 256;
#pragma unroll
    for (int p = 0; p < 8; ++p) {
      const int cc = p * 4 + ty;
      const unsigned v =
          ((const unsigned*)(codes + (size_t)(c0 + cc) * nslice + nbase))[lane];
      ctile[cc * 65 + lane] = v;
    }
  }
  __syncthreads();
  const unsigned char* ct8 = (const unsigned char*)ctile;
  const int cc  = threadIdx.x & 31;        // channel within tile
  const int nn0 = threadIdx.x >> 5;        // 0..7
  const float* cbrow = cbs + cc * KK;
  float* orow = out + (size_t)(n0_base + tn * 256) * CCH + c0 + cc;
#pragma unroll 4
  for (int p = 0; p < 32; ++p) {
    const int n = p * 8 + nn0;
    const unsigned code = ct8[cc * 260 + n];
    orow[(size_t)n * CCH] = cbrow[code];
  }
}

// ---------------------------------------------------------------------------
// Fallback (round-1 kernel): TA-path gather, used only if workspace is tiny.
// ---------------------------------------------------------------------------
#define ROWS_PER_BLOCK 512
#define NGROUPS 16
#define GCH (CCH / NGROUPS)

template <typename TabT>
__global__ __launch_bounds__(256, 8) void gather_kernel(
    const i32x4* __restrict__ left, const i32x4* __restrict__ right,
    const TabT* __restrict__ tab, const float* __restrict__ cb,
    f32x4* __restrict__ out, int nrows) {
  __shared__ float cbs[GCH * KK];
  const int g     = blockIdx.x & (NGROUPS - 1);
  const int chunk = blockIdx.x / NGROUPS;
  const int q     = threadIdx.x & 3;
  const int rsub  = threadIdx.x >> 2;
  {
    const f32x4* cbg = (const f32x4*)(cb + (size_t)(g * GCH) * KK);
    f32x4* cbl = (f32x4*)cbs;
#pragma unroll
    for (int i = 0; i < 4; ++i) cbl[threadIdx.x + i * 256] = cbg[threadIdx.x + i * 256];
  }
  __syncthreads();
  const int cbase  = g * GCH + q * 4;
  const TabT* t0   = tab + (size_t)cbase * (KK * KK);
  const int vecoff = g * 4 + q;
  const float* cq  = cbs + (q * 4) * KK;
  const int rbase = chunk * ROWS_PER_BLOCK;
#pragma unroll
  for (int it = 0; it < ROWS_PER_BLOCK / 32; ++it) {
    const int r0 = rbase + it * 32 + rsub;
    if (r0 >= nrows) break;
    const unsigned v0 = (unsigned)r0 * 64u + (unsigned)vecoff;
    i32x4 L0 = left[v0];
    i32x4 R0 = right[v0];
    unsigned c0 = (unsigned)t0[          (unsigned)(L0[0] * KK + R0[0])];
    unsigned c1 = (unsigned)t0[ 65536u + (unsigned)(L0[1] * KK + R0[1])];
    unsigned c2 = (unsigned)t0[131072u + (unsigned)(L0[2] * KK + R0[2])];
    unsigned c3 = (unsigned)t0[196608u + (unsigned)(L0[3] * KK + R0[3])];
    f32x4 o;
    o[0] = cq[       c0];
    o[1] = cq[KK   + c1];
    o[2] = cq[2*KK + c2];
    o[3] = cq[3*KK + c3];
    ((f32x4*)out)[v0] = o;
  }
}

extern "C" void kernel_launch(void* const* d_in, const int* in_sizes, int n_in,
                              void* d_out, int out_size, void* d_ws, size_t ws_size,
                              hipStream_t stream) {
  const int*   left  = (const int*)d_in[0];
  const int*   right = (const int*)d_in[1];
  const int*   wt    = (const int*)d_in[2];   // [C, K, K] int32
  const float* cb    = (const float*)d_in[3]; // [C, K] float32
  float* out = (float*)d_out;

  const int nrows = in_sizes[0] / CCH;        // 262144
  const int tab_elems = CCH * KK * KK;        // 16,777,216
  const size_t tab_bytes = (size_t)tab_elems; // u8 table = 16 MB

  // Pick smallest slicing S (1..32) whose workspace fits:
  //   need = 16 MB table + (C*nslice*2) LRt + (C*nslice) codes = 16M + 768*nslice
  int S = 0;
  for (int s = 1; s <= 32; s <<= 1) {
    if (nrows % (s * 8192)) continue;         // keep all kernel divisibility
    size_t need = tab_bytes + (size_t)768 * (size_t)(nrows / s);
    if (need <= ws_size) { S = s; break; }
  }

  if (S) {
    unsigned char* tab8 = (unsigned char*)d_ws;
    int n4 = tab_elems / 4;
    compress_table_kernel<<<n4 / 256, 256, 0, stream>>>(
        (const int4*)wt, (uchar4*)tab8, n4);

    const int nslice = nrows / S;
    unsigned short* LRt = (unsigned short*)((char*)d_ws + tab_bytes);
    unsigned char* codes = (unsigned char*)d_ws + tab_bytes + (size_t)512 * nslice;
    const int nsub = (nslice >= 32768) ? (nslice / 32768) : 1;

    for (int h = 0; h < S; ++h) {
      const int n0 = h * nslice;
      transpose_pack_kernel<<<(nslice / 64) * 4, 256, 0, stream>>>(
          left, right, LRt, n0, nslice);
      code_gather_kernel<<<nsub * CCH, 256, 0, stream>>>(
          LRt, tab8, codes, nslice, nsub);
      codebook_transpose_kernel<<<(nslice / 256) * 8, 256, 0, stream>>>(
          codes, cb, out, n0, nslice);
    }
  } else if (ws_size >= tab_bytes) {
    // Fallback: round-1 TA-path gather with u8 table.
    unsigned char* tab8 = (unsigned char*)d_ws;
    int n4 = tab_elems / 4;
    compress_table_kernel<<<n4 / 256, 256, 0, stream>>>(
        (const int4*)wt, (uchar4*)tab8, n4);
    const int blocks = ((nrows + ROWS_PER_BLOCK - 1) / ROWS_PER_BLOCK) * NGROUPS;
    gather_kernel<unsigned char><<<blocks, 256, 0, stream>>>(
        (const i32x4*)left, (const i32x4*)right, tab8, cb, (f32x4*)out, nrows);
  } else {
    // Last resort: gather directly from int32 table.
    const int blocks = ((nrows + ROWS_PER_BLOCK - 1) / ROWS_PER_BLOCK) * NGROUPS;
    gather_kernel<int><<<blocks, 256, 0, stream>>>(
        (const i32x4*)left, (const i32x4*)right, wt, cb, (f32x4*)out, nrows);
  }
}